// Round 6
// baseline (490.925 us; speedup 1.0000x reference)
//
#include <hip/hip_runtime.h>
#include <hip/hip_bf16.h>
#include <stdint.h>

typedef __hip_bfloat16 bf16;
typedef __attribute__((ext_vector_type(8))) short bf16x8;   // 8 bf16 = 4 VGPRs (MFMA A/B frag)
typedef __attribute__((ext_vector_type(4))) float f32x4;    // MFMA C/D frag + 16B loads
typedef __attribute__((ext_vector_type(4))) short s16x4;    // 8B bf16 store

constexpr int D_MODEL   = 2048;
constexpr int NUM_HEADS = 16;
constexpr int HEAD_DIM  = 128;
constexpr int BATCH     = 2;
constexpr int SEQ       = 2048;

// async global->LDS, 16B per lane; LDS dest must be wave-uniform base + lane*16
__device__ __forceinline__ void gload_lds16(const bf16* g, bf16* l) {
    __builtin_amdgcn_global_load_lds(
        (const __attribute__((address_space(1))) void*)g,
        (__attribute__((address_space(3))) void*)l, 16, 0, 0);
}

// ---------------------------------------------------------------------------
// fp32 -> bf16 bulk convert, up to 7 tensors in one launch (blockIdx.y selects)
// ---------------------------------------------------------------------------
struct CvtArgs { const float* src[7]; bf16* dst[7]; int n8[7]; };

__global__ __launch_bounds__(256)
void cvt_multi(CvtArgs a)
{
    const int t = blockIdx.y;
    const float* __restrict__ s = a.src[t];
    bf16* __restrict__ d = a.dst[t];
    const int n8 = a.n8[t];
    for (int i = blockIdx.x * 256 + threadIdx.x; i < n8; i += gridDim.x * 256) {
        f32x4 x = *(const f32x4*)(s + (size_t)i * 8);
        f32x4 y = *(const f32x4*)(s + (size_t)i * 8 + 4);
        bf16 t8[8] = { __float2bfloat16(x[0]), __float2bfloat16(x[1]),
                       __float2bfloat16(x[2]), __float2bfloat16(x[3]),
                       __float2bfloat16(y[0]), __float2bfloat16(y[1]),
                       __float2bfloat16(y[2]), __float2bfloat16(y[3]) };
        *(bf16x8*)(d + (size_t)i * 8) = *(const bf16x8*)t8;
    }
}

// ---------------------------------------------------------------------------
// GEMM core v2: C[M,N] = A[M,K] @ W[N,K]^T + bias[N]
// 128x128 tile, BK=32. Double-buffered async staging (global_load_lds 16B,
// XOR-swizzled global chunk -> linear LDS), ONE barrier per K-iter:
//   barrier (drains tile t) -> issue async t+1 into other buffer -> compute t.
// Frag read of global chunk j of row r sits at LDS chunk r*4 + (j ^ (r&3)).
// ---------------------------------------------------------------------------
template <typename TC, bool TRANS_PERM>
__device__ __forceinline__
void gemm_body(const bf16* __restrict__ A, const bf16* __restrict__ W,
               const float* __restrict__ bias, TC* __restrict__ C,
               int M, int N, int K)
{
    constexpr int BM = 128, BN = 128, BK = 32;
    __shared__ bf16 sA[2][BM * BK];        // 2 x 8 KB
    __shared__ bf16 sB[2][BN * BK];        // 2 x 8 KB

    const int tid  = threadIdx.x;
    const int wave = tid >> 6, lane = tid & 63;
    const int quad = lane >> 4, l16 = lane & 15;
    const int wr = wave >> 1, wc = wave & 1;
    const int m0 = blockIdx.y * BM, n0 = blockIdx.x * BN;

    // stage K-tile k0 into buffer bi (async, swizzled)
    auto stage = [&](int k0, int bi) {
        bf16* sAb = sA[bi];
        bf16* sBb = sB[bi];
#pragma unroll
        for (int s = 0; s < 2; s++) {
            int c = s * 256 + wave * 64 + lane;   // wave-uniform base + lane
            int row = c >> 2, gs = c & 3;
            int g = gs ^ (row & 3);
            gload_lds16(&A[(size_t)(m0 + row) * K + k0 + g * 8], sAb + (size_t)c * 8);
            gload_lds16(&W[(size_t)(n0 + row) * K + k0 + g * 8], sBb + (size_t)c * 8);
        }
    };

    f32x4 acc[4][4];
#pragma unroll
    for (int i = 0; i < 4; i++)
#pragma unroll
        for (int j = 0; j < 4; j++) acc[i][j] = (f32x4){0.f, 0.f, 0.f, 0.f};

    const int NIT = K / BK;                // 64
    stage(0, 0);

    for (int it = 0; it < NIT; ++it) {
        __syncthreads();                   // drains tile-it loads + sync
        if (it + 1 < NIT) stage((it + 1) * BK, (it + 1) & 1);

        const bf16* sAc = sA[it & 1];
        const bf16* sBc = sB[it & 1];
        const int sw = quad ^ (l16 & 3);   // swizzled chunk for col=quad*8

        bf16x8 af[4], bfr[4];
#pragma unroll
        for (int i = 0; i < 4; i++) {
            int row = wr * 64 + i * 16 + l16;
            af[i]  = *(const bf16x8*)&sAc[((size_t)row * 4 + sw) * 8];
        }
#pragma unroll
        for (int j = 0; j < 4; j++) {
            int row = wc * 64 + j * 16 + l16;
            bfr[j] = *(const bf16x8*)&sBc[((size_t)row * 4 + sw) * 8];
        }
#pragma unroll
        for (int i = 0; i < 4; i++)
#pragma unroll
            for (int j = 0; j < 4; j++)
                acc[i][j] = __builtin_amdgcn_mfma_f32_16x16x32_bf16(af[i], bfr[j], acc[i][j], 0, 0, 0);
    }

    // epilogue: C/D layout col=lane&15, row=quad*4+reg
#pragma unroll
    for (int j = 0; j < 4; j++) {
        int col = n0 + wc * 64 + j * 16 + l16;
        float bv = bias[col];
#pragma unroll
        for (int i = 0; i < 4; i++) {
            if constexpr (TRANS_PERM) {
                // V output: [b][h][dh][s'] with the flash key-permutation applied
                // within each 64-token group: pos p = c*32 + qh*8 + t*4 + r holds
                // key (2c+t)*16 + qh*4 + r.
                int row0 = m0 + wr * 64 + i * 16 + quad * 4;     // r = 0..3 run
                int g    = row0 & 63;                            // g & 3 == 0
                int tau  = g >> 4, qh = (g >> 2) & 3;
                int pp   = (tau >> 1) * 32 + qh * 8 + (tau & 1) * 4;
                int sp   = ((row0 & 2047) & ~63) | pp;
                size_t idx = (size_t)(row0 >> 11) * ((size_t)D_MODEL * SEQ)
                           + (size_t)col * SEQ + sp;
                bf16 t4[4];
#pragma unroll
                for (int r = 0; r < 4; r++) t4[r] = __float2bfloat16(acc[i][j][r] + bv);
                *(s16x4*)&C[idx] = *(const s16x4*)t4;
            } else {
#pragma unroll
                for (int r = 0; r < 4; r++) {
                    int row = m0 + wr * 64 + i * 16 + quad * 4 + r;
                    if constexpr (sizeof(TC) == 2)
                        C[(size_t)row * N + col] = (TC)__float2bfloat16(acc[i][j][r] + bv);
                    else
                        C[(size_t)row * N + col] = (TC)(acc[i][j][r] + bv);
                }
            }
        }
    }
}

template <typename TC, bool TRANS_PERM>
__global__ __launch_bounds__(256, 2)
void gemm_bf16(const bf16* __restrict__ A, const bf16* __restrict__ W,
               const float* __restrict__ bias, TC* __restrict__ C,
               int M, int N, int K)
{
    gemm_body<TC, TRANS_PERM>(A, W, bias, C, M, N, K);
}

// fused Q+K+V projections: blockIdx.z selects tensor; z==2 is V (trans+perm)
struct QkvArgs { const bf16* A[3]; const bf16* W[3]; const float* bias[3]; bf16* C[3]; };

__global__ __launch_bounds__(256, 2)
void gemm_qkv(QkvArgs ga, int M, int N, int K)
{
    const int z = blockIdx.z;
    if (z == 2) gemm_body<bf16, true >(ga.A[2], ga.W[2], ga.bias[2], ga.C[2], M, N, K);
    else        gemm_body<bf16, false>(ga.A[z], ga.W[z], ga.bias[z], ga.C[z], M, N, K);
}

// fused Q+K only (fallback when ws is tight)
struct QkArgs { const bf16* A[2]; const bf16* W[2]; const float* bias[2]; bf16* C[2]; };

__global__ __launch_bounds__(256, 2)
void gemm_qk(QkArgs ga, int M, int N, int K)
{
    const int z = blockIdx.z;
    gemm_body<bf16, false>(ga.A[z], ga.W[z], ga.bias[z], ga.C[z], M, N, K);
}

// ---------------------------------------------------------------------------
// Flash attention v3: operand-swapped (S^T/O^T), no-max softmax, P in regs,
// double-buffered async K/V staging (global_load_lds 16B, XOR-swizzled LDS),
// ONE barrier per K-tile iteration.
// ---------------------------------------------------------------------------
__global__ __launch_bounds__(256)
void flash_attn_kernel(const bf16* __restrict__ Qp, const bf16* __restrict__ Kp,
                       const bf16* __restrict__ Vt, bf16* __restrict__ Op)
{
    constexpr int BQ = 128, BKV = 64, DH = 128;
    __shared__ bf16 sK[2][BKV * DH];       // 2 x 16 KB
    __shared__ bf16 sV[2][DH * BKV];       // 2 x 16 KB

    const int tid  = threadIdx.x;
    const int wave = tid >> 6, lane = tid & 63;
    const int quad = lane >> 4, l16 = lane & 15;
    const int q0 = blockIdx.x * BQ;
    const int h  = blockIdx.y;
    const int b  = blockIdx.z;

    const size_t base  = (size_t)b * SEQ * D_MODEL + (size_t)h * HEAD_DIM;
    const size_t basev = ((size_t)b * NUM_HEADS + h) * (size_t)HEAD_DIM * SEQ;
    const bf16* Kb = Kp + base;
    const bf16* Vb = Vt + basev;

    auto stage = [&](int t, int bi) {
        const bf16* Kt = Kb + (size_t)t * BKV * D_MODEL;
        const bf16* Vtile = Vb + (size_t)t * BKV;
        bf16* sKb = sK[bi];
        bf16* sVb = sV[bi];
#pragma unroll
        for (int s = 0; s < 4; s++) {
            int c = s * 256 + wave * 64 + lane;            // 0..1023
            int row = c >> 4, gs = c & 15;
            int g = gs ^ (row & 15);
            gload_lds16(Kt + (size_t)row * D_MODEL + g * 8, sKb + (size_t)c * 8);
        }
#pragma unroll
        for (int s = 0; s < 4; s++) {
            int c = s * 256 + wave * 64 + lane;            // 0..1023
            int dh = c >> 3, gs = c & 7;
            int g = gs ^ (dh & 7);
            gload_lds16(Vtile + (size_t)dh * SEQ + g * 8, sVb + (size_t)c * 8);
        }
    };

    // Q B-frags, resident: B[n = q = l16][k = dh = kk*32+quad*8], 2 q-tiles/wave
    bf16x8 bq[2][4];
#pragma unroll
    for (int nt = 0; nt < 2; nt++)
#pragma unroll
        for (int kk = 0; kk < 4; kk++)
            bq[nt][kk] = *(const bf16x8*)&Qp[base +
                (size_t)(q0 + wave * 32 + nt * 16 + l16) * D_MODEL + kk * 32 + quad * 8];

    f32x4 oacc[2][8];                      // O^T: (dh = mt*16+quad*4+r, q = l16)
#pragma unroll
    for (int nt = 0; nt < 2; nt++)
#pragma unroll
        for (int mt = 0; mt < 8; mt++) oacc[nt][mt] = (f32x4){0.f, 0.f, 0.f, 0.f};

    float lsum[2] = {0.f, 0.f};            // per-lane partial softmax denominator

    const float SCL2E = 0.08838834764831845f * 1.4426950408889634f; // 1/sqrt(128)*log2(e)
    constexpr int NT = SEQ / BKV;          // 32

    stage(0, 0);

    for (int t = 0; t < NT; ++t) {
        __syncthreads();                   // drains tile-t loads (vmcnt) + sync
        if (t + 1 < NT) stage(t + 1, (t + 1) & 1);   // async prefetch, other buf

        const bf16* sKc = sK[t & 1];
        const bf16* sVc = sV[t & 1];

        // S^T = K Q^T : rows = keys (4 tiles of 16), cols = q (2 tiles/wave)
        f32x4 sacc[2][4];
#pragma unroll
        for (int nt = 0; nt < 2; nt++)
#pragma unroll
            for (int kt = 0; kt < 4; kt++) sacc[nt][kt] = (f32x4){0.f, 0.f, 0.f, 0.f};
#pragma unroll
        for (int kk = 0; kk < 4; kk++) {
            bf16x8 ak[4];
#pragma unroll
            for (int kt = 0; kt < 4; kt++) {
                int row = kt * 16 + l16;
                int g   = (kk * 4 + quad) ^ l16;           // row&15 == l16
                ak[kt] = *(const bf16x8*)&sKc[(size_t)row * DH + g * 8];
            }
#pragma unroll
            for (int nt = 0; nt < 2; nt++)
#pragma unroll
                for (int kt = 0; kt < 4; kt++)
                    sacc[nt][kt] = __builtin_amdgcn_mfma_f32_16x16x32_bf16(ak[kt], bq[nt][kk], sacc[nt][kt], 0, 0, 0);
        }

        // exp (no max subtraction; clamped) + denominator + pack P^T B-frags
        bf16x8 pb[2][2];
#pragma unroll
        for (int nt = 0; nt < 2; nt++) {
            bf16 tmp[16];
#pragma unroll
            for (int kt = 0; kt < 4; kt++) {
#pragma unroll
                for (int r = 0; r < 4; r++) {
                    float p = exp2f(fminf(sacc[nt][kt][r] * SCL2E, 60.f));
                    lsum[nt] += p;
                    tmp[(kt >> 1) * 8 + (kt & 1) * 4 + r] = __float2bfloat16(p);
                }
            }
            pb[nt][0] = *(const bf16x8*)&tmp[0];
            pb[nt][1] = *(const bf16x8*)&tmp[8];
        }

        // O^T += V^T P : A = V^T frag from LDS, B = P^T frag (in-register)
#pragma unroll
        for (int c = 0; c < 2; c++) {
#pragma unroll
            for (int mt = 0; mt < 8; mt++) {
                int row = mt * 16 + l16;
                int g   = (c * 4 + quad) ^ (l16 & 7);      // row&7 == l16&7
                bf16x8 av = *(const bf16x8*)&sVc[(size_t)row * BKV + g * 8];
#pragma unroll
                for (int nt = 0; nt < 2; nt++)
                    oacc[nt][mt] = __builtin_amdgcn_mfma_f32_16x16x32_bf16(av, pb[nt][c], oacc[nt][mt], 0, 0, 0);
            }
        }
    }

    // reduce denominator across the 4 quads holding the same q (= l16)
#pragma unroll
    for (int nt = 0; nt < 2; nt++) {
        float v = lsum[nt];
        v += __shfl_xor(v, 16);
        v += __shfl_xor(v, 32);
        lsum[nt] = v;
    }

    // epilogue: O[q][dh] = O^T / l ; 4 consecutive dh per reg quad -> 8B stores
#pragma unroll
    for (int nt = 0; nt < 2; nt++) {
        float inv = 1.f / lsum[nt];
        int row = q0 + wave * 32 + nt * 16 + l16;
#pragma unroll
        for (int mt = 0; mt < 8; mt++) {
            bf16 t4[4];
#pragma unroll
            for (int r = 0; r < 4; r++) t4[r] = __float2bfloat16(oacc[nt][mt][r] * inv);
            *(s16x4*)&Op[base + (size_t)row * D_MODEL + mt * 16 + quad * 4] = *(const s16x4*)t4;
        }
    }
}

// ---------------------------------------------------------------------------
extern "C" void kernel_launch(void* const* d_in, const int* in_sizes, int n_in,
                              void* d_out, int out_size, void* d_ws, size_t ws_size,
                              hipStream_t stream)
{
    const float* query  = (const float*)d_in[0];
    const float* key_in = (const float*)d_in[1];
    const float* value  = (const float*)d_in[2];
    const float* Wq = (const float*)d_in[3];
    const float* bq = (const float*)d_in[4];
    const float* Wk = (const float*)d_in[5];
    const float* bk = (const float*)d_in[6];
    const float* Wv = (const float*)d_in[7];
    const float* bv = (const float*)d_in[8];
    const float* Wo = (const float*)d_in[9];
    const float* bo = (const float*)d_in[10];
    float* out = (float*)d_out;

    const int tokens = BATCH * SEQ;                          // 4096
    const size_t nAct = (size_t)tokens * D_MODEL;            // 8.4M elems
    const size_t nW   = (size_t)D_MODEL * D_MODEL;           // 4.2M elems

    const bool fused_qkv = ws_size >= (6 * nAct + 4 * nW) * sizeof(bf16);

    bf16* p = (bf16*)d_ws;
    bf16* qb  = p; p += nAct;      // bf16 activations
    bf16* kb  = p; p += nAct;
    bf16* vb  = p; p += nAct;
    bf16* wqb = p; p += nW;        // bf16 weights
    bf16* wkb = p; p += nW;
    bf16* wvb = p; p += nW;
    bf16* wob = p; p += nW;
    bf16* qp  = p; p += nAct;      // Q,K projections
    bf16* kp  = p; p += nAct;
    bf16* vpT;                     // V projection (transposed+permuted)
    if (fused_qkv) { vpT = p; p += nAct; }
    else           { vpT = qb; }   // fallback: alias (QK launch consumes qb first)
    bf16* ap = fused_qkv ? qb : kb; // attn out: aliases an activation consumed earlier

    // 1. fp32 -> bf16 (one launch)
    CvtArgs ca;
    ca.src[0] = query;  ca.dst[0] = qb;  ca.n8[0] = (int)(nAct / 8);
    ca.src[1] = key_in; ca.dst[1] = kb;  ca.n8[1] = (int)(nAct / 8);
    ca.src[2] = value;  ca.dst[2] = vb;  ca.n8[2] = (int)(nAct / 8);
    ca.src[3] = Wq;     ca.dst[3] = wqb; ca.n8[3] = (int)(nW / 8);
    ca.src[4] = Wk;     ca.dst[4] = wkb; ca.n8[4] = (int)(nW / 8);
    ca.src[5] = Wv;     ca.dst[5] = wvb; ca.n8[5] = (int)(nW / 8);
    ca.src[6] = Wo;     ca.dst[6] = wob; ca.n8[6] = (int)(nW / 8);
    cvt_multi<<<dim3(512, 7), 256, 0, stream>>>(ca);

    // 2. projections
    if (fused_qkv) {
        QkvArgs qa;
        qa.A[0] = qb; qa.W[0] = wqb; qa.bias[0] = bq; qa.C[0] = qp;
        qa.A[1] = kb; qa.W[1] = wkb; qa.bias[1] = bk; qa.C[1] = kp;
        qa.A[2] = vb; qa.W[2] = wvb; qa.bias[2] = bv; qa.C[2] = vpT;
        dim3 g3(D_MODEL / 128, tokens / 128, 3);             // (16, 32, 3)
        gemm_qkv<<<g3, 256, 0, stream>>>(qa, tokens, D_MODEL, D_MODEL);
    } else {
        QkArgs qa;
        qa.A[0] = qb; qa.W[0] = wqb; qa.bias[0] = bq; qa.C[0] = qp;
        qa.A[1] = kb; qa.W[1] = wkb; qa.bias[1] = bk; qa.C[1] = kp;
        dim3 g2(D_MODEL / 128, tokens / 128, 2);             // (16, 32, 2)
        gemm_qk<<<g2, 256, 0, stream>>>(qa, tokens, D_MODEL, D_MODEL);
        dim3 gg(D_MODEL / 128, tokens / 128);
        gemm_bf16<bf16, true><<<gg, 256, 0, stream>>>(vb, wvb, bv, vpT, tokens, D_MODEL, D_MODEL);
    }

    // 3. attention
    dim3 ga(SEQ / 128, NUM_HEADS, BATCH);                    // (16, 16, 2)
    flash_attn_kernel<<<ga, 256, 0, stream>>>(qp, kp, vpT, ap);

    // 4. output projection (fp32 out)
    dim3 gg(D_MODEL / 128, tokens / 128);
    gemm_bf16<float, false><<<gg, 256, 0, stream>>>(ap, wob, bo, out, tokens, D_MODEL, D_MODEL);
}